// Round 10
// baseline (222.244 us; speedup 1.0000x reference)
//
#include <hip/hip_runtime.h>

// VecLocal2d R10: DIAGNOSTIC ABLATION ROUND. R4-R9 landed at main~40-50us
// across four structurally different schedules while every pipe-sum says
// ~15us. This round launches template<V> ablation variants (each x2 reps,
// >43us so they displace fillBuffer from rocprof top-5) BEFORE the real
// V0 pass (which fully overwrites co, so final output is unchanged).
//   V1: no COMPUTE (no A ds_reads / MFMA)      -> LDS-read-pipe theory
//   V2: no W path (no WISSUE / SCATTER)        -> W-convert/scatter theory
//   V3: no A staging (no gl_lds slots/restage) -> staging theory
//   V4: 1 store/phase (acc kept live)          -> store-drain theory
//   V0: full (authoritative, runs last)
// All barriers/waits unconditional & uniform (no hang risk); vmcnt waits
// only get looser when ops are removed. Rep-boundary BARA added (audited:
// rep2 prologue VM(15) covers 5 leftover stores + 9 W0).
// hz/t1/t2 + R3 fallback verbatim from R9 (passed, absmax 0.03125).

#define HW    32
#define CIN   32
#define COUT  64
#define FDIM  288
#define FPAD  296
#define NBK   160
#define HP    34
#define PLANE (NBK * CIN)      // 5120 shorts per (ih,jw) plane
#define SLOT_SH (3 * PLANE)    // 15360 shorts per jw-slot
#define WOFF  (4 * SLOT_SH)    // 61440 shorts: W region start
#define REPS  2

using f32x4  = __attribute__((ext_vector_type(4))) float;
using bf16x8 = __attribute__((ext_vector_type(8))) short;
using s16x4  = __attribute__((ext_vector_type(4))) short;

static __device__ inline unsigned short f2bf(float f) {
    unsigned u = __float_as_uint(f);
    u += 0x7FFFu + ((u >> 16) & 1u);   // round-to-nearest-even
    return (unsigned short)(u >> 16);
}
static __device__ inline void gl_lds16(const short* src, short* dst) {
    __builtin_amdgcn_global_load_lds(
        (const __attribute__((address_space(1))) unsigned int*)src,
        (__attribute__((address_space(3))) unsigned int*)dst, 16, 0, 0);
}
static constexpr size_t XC_BYTES = (size_t)HP * HP * PLANE * 2;       // 11,837,440
static constexpr size_t CO_BYTES = (size_t)1024 * COUT * NBK * 2;     // 20,971,520

// ---- hz ----
__global__ __launch_bounds__(256) void hz_kernel(short* __restrict__ xc)
{
    const int id = blockIdx.x;
    int h, w;
    if (id < 34)      { h = 0;  w = id; }
    else if (id < 68) { h = 33; w = id - 34; }
    else { const int e = id - 68; h = 1 + (e >> 1); w = (e & 1) * 33; }
    uint2* p = reinterpret_cast<uint2*>(xc + (size_t)(h * HP + w) * PLANE);
    const uint2 z = {0u, 0u};
#pragma unroll
    for (int r = 0; r < 5; ++r)
        p[threadIdx.x + r * 256] = z;
}

// ---- t1 (pre-swizzled planes) ----
__global__ __launch_bounds__(256) void t1_kernel(
    const float* __restrict__ x, short* __restrict__ xc)
{
    __shared__ short tile[HW][36];
    const int bid = blockIdx.x;
    const int bk  = bid >> 5;
    const int h   = bid & 31;
    const int tid = threadIdx.x;
    {
        const int c  = tid >> 3;
        const int w4 = (tid & 7) * 4;
        const float4 v = *reinterpret_cast<const float4*>(
            x + (size_t)(bk * 32 + c) * 1024 + h * 32 + w4);
        tile[w4 + 0][c] = (short)f2bf(v.x);
        tile[w4 + 1][c] = (short)f2bf(v.y);
        tile[w4 + 2][c] = (short)f2bf(v.z);
        tile[w4 + 3][c] = (short)f2bf(v.w);
    }
    __syncthreads();
    {
        const int w  = tid >> 3;
        const int cq = tid & 7;
        const uint2 pk = *reinterpret_cast<const uint2*>(&tile[w][cq * 4]);
        const int sidx = bk * 32 + ((cq * 4) ^ (((bk >> 1) & 3) << 3));
        *reinterpret_cast<uint2*>(
            xc + (size_t)((h + 1) * HP + (w + 1)) * PLANE + sidx) = pk;
    }
}

// ---- main (template ablation) ----
#define SB()  __builtin_amdgcn_sched_barrier(0)
#define VM(n) { asm volatile("s_waitcnt vmcnt(" #n ")" ::: "memory"); SB(); }
#define LG0BAR() { asm volatile("s_waitcnt lgkmcnt(0)" ::: "memory"); SB(); \
                   __builtin_amdgcn_s_barrier(); SB(); }
#define BARA() { asm volatile("s_waitcnt lgkmcnt(0)" ::: "memory"); SB(); \
                 __builtin_amdgcn_s_barrier(); SB(); }

template<int V>
__global__ __launch_bounds__(512) void local2d_v_kernel(
    const short* __restrict__ xc,
    const float* __restrict__ w,
    short* __restrict__ co)
{
    __shared__ __align__(1024) short Sl[WOFF + COUT * FPAD];  // 160,768 B

    const int hb = blockIdx.x;                  // 256 = i(32) * jt(8)
    const int lb = (hb & 7) * 32 + (hb >> 3);   // XCD-chunked, bijective
    const int i  = lb >> 3;
    const int jt = lb & 7;
    const int j0 = jt * 4;
    const int tid = threadIdx.x;

    const int wave = tid >> 6;
    const int lane = tid & 63;
    const int nt   = wave & 3;
    const int mh   = wave >> 2;
    const int l15  = lane & 15;
    const int lg   = lane >> 4;
    const int lg8  = lg * 8;

    short* WL = Sl + WOFF;

    int rowbyte[5];
#pragma unroll
    for (int mt = 0; mt < 5; ++mt) {
        const int bk = mh * 80 + mt * 16 + l15;
        rowbyte[mt] = (bk * 64 + lg * 16) ^ (((bk >> 1) & 3) << 4);
    }

    float4 wv0[9], wv1[9];
    const f32x4 z4 = {0.f, 0.f, 0.f, 0.f};
    f32x4 acc0, acc1, acc2, acc3, acc4;

#define WISSUE(dst, pp) {                                                  \
        const float* wp = w + (size_t)((i * 32) + j0 + (pp)) * (COUT * FDIM); \
        _Pragma("unroll")                                                  \
        for (int q = 0; q < 9; ++q) {                                      \
            const int g  = tid + q * 512;                                  \
            const int o2 = g / 72;                                         \
            const int f4 = (g - o2 * 72) * 4;                              \
            dst[q] = *reinterpret_cast<const float4*>(wp + o2 * FDIM + f4);\
        } SB(); }

#define SCATTER(src) {                                                     \
        _Pragma("unroll")                                                  \
        for (int q = 0; q < 9; ++q) {                                      \
            const int g  = tid + q * 512;                                  \
            const int o2 = g / 72;                                         \
            const int f4 = (g - o2 * 72) * 4;                              \
            const float vv[4] = {src[q].x, src[q].y, src[q].z, src[q].w};  \
            short* wrow = WL + o2 * FPAD;                                  \
            _Pragma("unroll")                                              \
            for (int e = 0; e < 4; ++e) {                                  \
                const int f = f4 + e; const int c = f / 9;                 \
                const int cell = f - c * 9;                                \
                wrow[cell * 32 + c] = (short)f2bf(vv[e]); } } SB(); }

#define RISSUE(s) {                                                        \
        if (tid < 480) {                                                   \
            _Pragma("unroll")                                              \
            for (int r = 0; r < 4; ++r) {                                  \
                const int u  = tid + r * 480;                              \
                const int pl = u / 640;                                    \
                const int cu = u - pl * 640;                               \
                const short* src = xc + (size_t)((i + pl) * HP + (j0 + 4 + (s))) * PLANE + cu * 8; \
                gl_lds16(src, Sl + (size_t)((s) * SLOT_SH) + (size_t)u * 8); \
            } } SB(); }

#define COMPUTE(p) {                                                       \
        acc0 = z4; acc1 = z4; acc2 = z4; acc3 = z4; acc4 = z4;             \
        const short* bp = WL + (nt * 16 + l15) * FPAD + lg8;               \
        _Pragma("unroll")                                                  \
        for (int kc = 0; kc < 9; ++kc) {                                   \
            const int kh   = kc / 3;                                       \
            const int kw   = kc - kh * 3;                                  \
            const int slot = ((p) + kw) & 3;                               \
            const char* ab = (const char*)Sl + slot * (SLOT_SH * 2) + kh * (PLANE * 2); \
            const bf16x8 b  = *reinterpret_cast<const bf16x8*>(bp + kc * 32); \
            const bf16x8 a0 = *reinterpret_cast<const bf16x8*>(ab + rowbyte[0]); \
            const bf16x8 a1 = *reinterpret_cast<const bf16x8*>(ab + rowbyte[1]); \
            const bf16x8 a2 = *reinterpret_cast<const bf16x8*>(ab + rowbyte[2]); \
            const bf16x8 a3 = *reinterpret_cast<const bf16x8*>(ab + rowbyte[3]); \
            const bf16x8 a4 = *reinterpret_cast<const bf16x8*>(ab + rowbyte[4]); \
            acc0 = __builtin_amdgcn_mfma_f32_16x16x32_bf16(a0, b, acc0, 0, 0, 0); \
            acc1 = __builtin_amdgcn_mfma_f32_16x16x32_bf16(a1, b, acc1, 0, 0, 0); \
            acc2 = __builtin_amdgcn_mfma_f32_16x16x32_bf16(a2, b, acc2, 0, 0, 0); \
            acc3 = __builtin_amdgcn_mfma_f32_16x16x32_bf16(a3, b, acc3, 0, 0, 0); \
            acc4 = __builtin_amdgcn_mfma_f32_16x16x32_bf16(a4, b, acc4, 0, 0, 0); \
        } }

#define STOREFULL(p) {                                                     \
        const int pix = i * 32 + j0 + (p);                                 \
        const int o3  = nt * 16 + l15;                                     \
        const size_t cb = ((size_t)pix * COUT + o3) * NBK + mh * 80 + lg * 4; \
        { s16x4 s_; s_.x = (short)f2bf(acc0[0]); s_.y = (short)f2bf(acc0[1]); \
          s_.z = (short)f2bf(acc0[2]); s_.w = (short)f2bf(acc0[3]);        \
          *reinterpret_cast<s16x4*>(co + cb + 0) = s_; }                   \
        { s16x4 s_; s_.x = (short)f2bf(acc1[0]); s_.y = (short)f2bf(acc1[1]); \
          s_.z = (short)f2bf(acc1[2]); s_.w = (short)f2bf(acc1[3]);        \
          *reinterpret_cast<s16x4*>(co + cb + 16) = s_; }                  \
        { s16x4 s_; s_.x = (short)f2bf(acc2[0]); s_.y = (short)f2bf(acc2[1]); \
          s_.z = (short)f2bf(acc2[2]); s_.w = (short)f2bf(acc2[3]);        \
          *reinterpret_cast<s16x4*>(co + cb + 32) = s_; }                  \
        { s16x4 s_; s_.x = (short)f2bf(acc3[0]); s_.y = (short)f2bf(acc3[1]); \
          s_.z = (short)f2bf(acc3[2]); s_.w = (short)f2bf(acc3[3]);        \
          *reinterpret_cast<s16x4*>(co + cb + 48) = s_; }                  \
        { s16x4 s_; s_.x = (short)f2bf(acc4[0]); s_.y = (short)f2bf(acc4[1]); \
          s_.z = (short)f2bf(acc4[2]); s_.w = (short)f2bf(acc4[3]);        \
          *reinterpret_cast<s16x4*>(co + cb + 64) = s_; } }

#define STOREMIN(p) {                                                      \
        const int pix = i * 32 + j0 + (p);                                 \
        const int o3  = nt * 16 + l15;                                     \
        const size_t cb = ((size_t)pix * COUT + o3) * NBK + mh * 80 + lg * 4; \
        const float s_ = acc0[0] + acc1[0] + acc2[0] + acc3[0] + acc4[0];  \
        co[cb] = (short)f2bf(s_); }                     /* keeps MFMA live */

#define COMPUTE_G(p) { if constexpr (V != 1) { COMPUTE(p) }                \
                       else { acc0 = z4; acc1 = z4; acc2 = z4; acc3 = z4; acc4 = z4; } }
#define STORE_G(p)   { if constexpr (V != 4) { STOREFULL(p) } else { STOREMIN(p) } }

    for (int rep = 0; rep < REPS; ++rep) {
        BARA()   // rep boundary: prev rep's compute reads done before restage

        // ================= prologue =================
        if constexpr (V != 2) { WISSUE(wv0, 0) }
        if constexpr (V != 3) {
#pragma unroll
            for (int r = 0; r < 15; ++r) {
                const int u   = tid + r * 512;
                const int s   = u / 1920;
                const int rem = u - s * 1920;
                const int pl  = rem / 640;
                const int cu  = rem - pl * 640;
                const short* src = xc + (size_t)((i + pl) * HP + (j0 + s)) * PLANE + cu * 8;
                gl_lds16(src, Sl + (size_t)u * 8);
            }
            SB();
        }
        VM(15)
        if constexpr (V != 2) { SCATTER(wv0) WISSUE(wv1, 1) }
        VM(9)
        LG0BAR()

        // ================= phase 0 =================
        COMPUTE_G(0) STORE_G(0)
        BARA()
        VM(0)
        if constexpr (V != 2) { SCATTER(wv1) WISSUE(wv0, 2) }
        LG0BAR()

        // ================= phase 1 =================
        if constexpr (V != 3) { RISSUE(0) }
        COMPUTE_G(1) STORE_G(1)
        BARA()
        VM(4)
        if constexpr (V != 2) { SCATTER(wv0) WISSUE(wv1, 3) }
        VM(9)
        LG0BAR()

        // ================= phase 2 =================
        if constexpr (V != 3) { RISSUE(1) }
        COMPUTE_G(2) STORE_G(2)
        BARA()
        VM(4)
        if constexpr (V != 2) { SCATTER(wv1) }
        VM(0)
        LG0BAR()

        // ================= phase 3 =================
        COMPUTE_G(3) STORE_G(3)
    }

#undef WISSUE
#undef SCATTER
#undef RISSUE
#undef COMPUTE
#undef STOREFULL
#undef STOREMIN
#undef COMPUTE_G
#undef STORE_G
}

// ---- t2 ----
__global__ __launch_bounds__(256) void t2_kernel(
    const short* __restrict__ co,
    const float* __restrict__ bias,
    float* __restrict__ out)
{
    __shared__ short tl[32][36];
    const int b    = blockIdx.x;          // 10240 = o(64) * bkT(5) * pixT(32)
    const int o    = b & 63;
    const int rest = b >> 6;
    const int bkT  = rest % 5;
    const int pixT = rest / 5;
    const int tid  = threadIdx.x;
    {
        const int p  = tid >> 3;
        const int bq = tid & 7;
        const int pix = pixT * 32 + p;
        const s16x4 v = *reinterpret_cast<const s16x4*>(
            co + ((size_t)pix * COUT + o) * NBK + bkT * 32 + bq * 4);
        *reinterpret_cast<s16x4*>(&tl[p][bq * 4]) = v;
    }
    __syncthreads();
    {
        const int bb = tid >> 3;
        const int pq = tid & 7;
        const int bk = bkT * 32 + bb;
        const int k  = bk % 10;
        const size_t pbase = (size_t)pixT * 32 + pq * 4;
        const float4 bv = *reinterpret_cast<const float4*>(
            bias + ((size_t)(k * COUT + o) << 10) + pbase);
        float4 r;
        r.x = __uint_as_float(((unsigned)(unsigned short)tl[pq * 4 + 0][bb]) << 16) + bv.x;
        r.y = __uint_as_float(((unsigned)(unsigned short)tl[pq * 4 + 1][bb]) << 16) + bv.y;
        r.z = __uint_as_float(((unsigned)(unsigned short)tl[pq * 4 + 2][bb]) << 16) + bv.z;
        r.w = __uint_as_float(((unsigned)(unsigned short)tl[pq * 4 + 3][bb]) << 16) + bv.w;
        *reinterpret_cast<float4*>(out + ((size_t)(bk * COUT + o) << 10) + pbase) = r;
    }
}

// ================= R3 fallback (proven; needs 10 MB ws) =================
__global__ __launch_bounds__(256) void xpose_kernel(
    const float* __restrict__ x, short* __restrict__ xc)
{
    __shared__ short tile[HW][36];
    const int bid = blockIdx.x;
    const int bk  = bid >> 5;
    const int h   = bid & 31;
    const int tid = threadIdx.x;
    {
        const int c  = tid >> 3;
        const int w4 = (tid & 7) * 4;
        const float4 v = *reinterpret_cast<const float4*>(
            x + (size_t)(bk * 32 + c) * 1024 + h * 32 + w4);
        tile[w4 + 0][c] = (short)f2bf(v.x);
        tile[w4 + 1][c] = (short)f2bf(v.y);
        tile[w4 + 2][c] = (short)f2bf(v.z);
        tile[w4 + 3][c] = (short)f2bf(v.w);
    }
    __syncthreads();
    {
        const int w  = tid >> 3;
        const int cq = tid & 7;
        const uint2 pk = *reinterpret_cast<const uint2*>(&tile[w][cq * 4]);
        *reinterpret_cast<uint2*>(
            xc + ((size_t)(bk * 1024 + h * 32 + w) * 32 + cq * 4)) = pk;
    }
}

__global__ __launch_bounds__(512, 4) void local2d_mfma2_kernel(
    const short* __restrict__ xc,
    const float* __restrict__ w,
    const float* __restrict__ bias,
    float* __restrict__ out)
{
    __shared__ short Wl[COUT * FPAD];
    const int hb  = blockIdx.x;
    const int lb  = (hb & 7) * 128 + (hb >> 3);
    const int i   = lb >> 5;
    const int j   = lb & 31;
    const int pix = i * HW + j;
    const int tid = threadIdx.x;
    {
        const float* wp = w + (size_t)pix * (COUT * FDIM);
#pragma unroll
        for (int p = 0; p < 9; ++p) {
            const int g  = tid + p * 512;
            const int o  = g / 72;
            const int f4 = (g - o * 72) * 4;
            const float4 v = *reinterpret_cast<const float4*>(wp + o * FDIM + f4);
            const float vv[4] = {v.x, v.y, v.z, v.w};
            short* wrow = &Wl[o * FPAD];
#pragma unroll
            for (int e = 0; e < 4; ++e) {
                const int f    = f4 + e;
                const int c    = f / 9;
                const int cell = f - c * 9;
                wrow[cell * 32 + c] = (short)f2bf(vv[e]);
            }
        }
    }
    __syncthreads();
    const int wave = tid >> 6;
    const int lane = tid & 63;
    const int nt   = wave & 3;
    const int mh   = wave >> 2;
    const int l15  = lane & 15;
    const int lg8  = (lane >> 4) * 8;
    f32x4 acc[5];
#pragma unroll
    for (int mt = 0; mt < 5; ++mt)
#pragma unroll
        for (int r = 0; r < 4; ++r) acc[mt][r] = 0.f;
    const short* xb[5];
#pragma unroll
    for (int mt = 0; mt < 5; ++mt) {
        const int bk = mh * 80 + mt * 16 + l15;
        xb[mt] = xc + (size_t)bk * (HW * HW * CIN) + lg8;
    }
    const short* bp = &Wl[(nt * 16 + l15) * FPAD + lg8];
#pragma unroll
    for (int kc = 0; kc < 9; ++kc) {
        const int kh = kc / 3;
        const int kw = kc - kh * 3;
        const int ih = i - 1 + kh;
        const int jw = j - 1 + kw;
        if ((unsigned)ih >= (unsigned)HW || (unsigned)jw >= (unsigned)HW)
            continue;
        const bf16x8 b = *reinterpret_cast<const bf16x8*>(bp + kc * 32);
        const int xoff = (ih * HW + jw) * CIN;
#pragma unroll
        for (int mt = 0; mt < 5; ++mt) {
            const bf16x8 a = *reinterpret_cast<const bf16x8*>(xb[mt] + xoff);
            acc[mt] = __builtin_amdgcn_mfma_f32_16x16x32_bf16(a, b, acc[mt], 0, 0, 0);
        }
    }
    const int o  = nt * 16 + l15;
    const int r0 = (lane >> 4) * 4;
#pragma unroll
    for (int mt = 0; mt < 5; ++mt) {
        const int bk0 = mh * 80 + mt * 16 + r0;
#pragma unroll
        for (int r = 0; r < 4; ++r) {
            const int bk = bk0 + r;
            const int k  = bk % 10;
            out[((size_t)(bk * COUT + o) << 10) + pix] =
                acc[mt][r] + bias[((size_t)(k * COUT + o) << 10) + pix];
        }
    }
}

extern "C" void kernel_launch(void* const* d_in, const int* in_sizes, int n_in,
                              void* d_out, int out_size, void* d_ws, size_t ws_size,
                              hipStream_t stream) {
    const float* x    = (const float*)d_in[0];
    const float* w    = (const float*)d_in[1];
    const float* bias = (const float*)d_in[2];
    float* out        = (float*)d_out;

    if (ws_size >= XC_BYTES + CO_BYTES) {
        short* xc = (short*)d_ws;
        short* co = (short*)((char*)d_ws + XC_BYTES);
        hipLaunchKernelGGL(hz_kernel, dim3(132), dim3(256), 0, stream, xc);
        hipLaunchKernelGGL(t1_kernel, dim3(5120), dim3(256), 0, stream, x, xc);
        // ---- diagnostic ablation dispatches (co garbage, overwritten) ----
        hipLaunchKernelGGL((local2d_v_kernel<1>), dim3(256), dim3(512), 0, stream, xc, w, co);
        hipLaunchKernelGGL((local2d_v_kernel<2>), dim3(256), dim3(512), 0, stream, xc, w, co);
        hipLaunchKernelGGL((local2d_v_kernel<3>), dim3(256), dim3(512), 0, stream, xc, w, co);
        hipLaunchKernelGGL((local2d_v_kernel<4>), dim3(256), dim3(512), 0, stream, xc, w, co);
        // ---- authoritative full pass ----
        hipLaunchKernelGGL((local2d_v_kernel<0>), dim3(256), dim3(512), 0, stream, xc, w, co);
        hipLaunchKernelGGL(t2_kernel, dim3(10240), dim3(256), 0, stream,
                           co, bias, out);
    } else {
        short* xc = (short*)d_ws;
        hipLaunchKernelGGL(xpose_kernel, dim3(5120), dim3(256), 0, stream, x, xc);
        hipLaunchKernelGGL(local2d_mfma2_kernel, dim3(1024), dim3(512), 0, stream,
                           xc, w, bias, out);
    }
}

// Round 11
// 53.009 us; speedup vs baseline: 4.1926x; 4.1926x over previous
//
#include <hip/hip_runtime.h>

// VecLocal2d R11 = R9 schedule with 2-DEEP W prefetch + setprio(MFMA).
// R10 ablation: warm body = 16us (marginal rep), cold-start ~24us = W HBM
// stream under-overlapped (1-phase flight, bursty demand, ~3.1 TB/s eff).
// R11 gives every W tile TWO compute phases of flight via wv0/wv1/wv2.
//
// vmcnt ledger (per wave; loads/stores FIFO-retire, stores counted):
//  pro:  W0[9] W1[9] S[15]            -> VM(24)=W0; scat0; VM(9)=S; BAR
//  ph0:  W2[9]; C0; st0[5]            -> VM(14)=W1 (W2+st0); scat1; BAR
//  ph1:  R0[4] W3[9]; C1; st1[5]      -> VM(23)=W2; scat2; VM(14)=R0; BAR
//  ph2:  R1[4]; C2; st2[5]            -> VM(14)=W3 (st1+R1+st2); scat3; VM(5)=R1; BAR
//  ph3:  C3; st3
// hz/t1(pre-swizzled)/t2/fallback verbatim from R9 (passed, absmax 0.03125).

#define HW    32
#define CIN   32
#define COUT  64
#define FDIM  288
#define FPAD  296
#define NBK   160
#define HP    34
#define PLANE (NBK * CIN)      // 5120 shorts per (ih,jw) plane
#define SLOT_SH (3 * PLANE)    // 15360 shorts per jw-slot
#define WOFF  (4 * SLOT_SH)    // 61440 shorts: W region start

using f32x4  = __attribute__((ext_vector_type(4))) float;
using bf16x8 = __attribute__((ext_vector_type(8))) short;
using s16x4  = __attribute__((ext_vector_type(4))) short;

static __device__ inline unsigned short f2bf(float f) {
    unsigned u = __float_as_uint(f);
    u += 0x7FFFu + ((u >> 16) & 1u);   // round-to-nearest-even
    return (unsigned short)(u >> 16);
}
static __device__ inline void gl_lds16(const short* src, short* dst) {
    __builtin_amdgcn_global_load_lds(
        (const __attribute__((address_space(1))) unsigned int*)src,
        (__attribute__((address_space(3))) unsigned int*)dst, 16, 0, 0);
}
static constexpr size_t XC_BYTES = (size_t)HP * HP * PLANE * 2;       // 11,837,440
static constexpr size_t CO_BYTES = (size_t)1024 * COUT * NBK * 2;     // 20,971,520

// ---- hz ----
__global__ __launch_bounds__(256) void hz_kernel(short* __restrict__ xc)
{
    const int id = blockIdx.x;
    int h, w;
    if (id < 34)      { h = 0;  w = id; }
    else if (id < 68) { h = 33; w = id - 34; }
    else { const int e = id - 68; h = 1 + (e >> 1); w = (e & 1) * 33; }
    uint2* p = reinterpret_cast<uint2*>(xc + (size_t)(h * HP + w) * PLANE);
    const uint2 z = {0u, 0u};
#pragma unroll
    for (int r = 0; r < 5; ++r)
        p[threadIdx.x + r * 256] = z;
}

// ---- t1 (pre-swizzled planes) ----
__global__ __launch_bounds__(256) void t1_kernel(
    const float* __restrict__ x, short* __restrict__ xc)
{
    __shared__ short tile[HW][36];
    const int bid = blockIdx.x;
    const int bk  = bid >> 5;
    const int h   = bid & 31;
    const int tid = threadIdx.x;
    {
        const int c  = tid >> 3;
        const int w4 = (tid & 7) * 4;
        const float4 v = *reinterpret_cast<const float4*>(
            x + (size_t)(bk * 32 + c) * 1024 + h * 32 + w4);
        tile[w4 + 0][c] = (short)f2bf(v.x);
        tile[w4 + 1][c] = (short)f2bf(v.y);
        tile[w4 + 2][c] = (short)f2bf(v.z);
        tile[w4 + 3][c] = (short)f2bf(v.w);
    }
    __syncthreads();
    {
        const int w  = tid >> 3;
        const int cq = tid & 7;
        const uint2 pk = *reinterpret_cast<const uint2*>(&tile[w][cq * 4]);
        const int sidx = bk * 32 + ((cq * 4) ^ (((bk >> 1) & 3) << 3));
        *reinterpret_cast<uint2*>(
            xc + (size_t)((h + 1) * HP + (w + 1)) * PLANE + sidx) = pk;
    }
}

// ---- main ----
#define SB()  __builtin_amdgcn_sched_barrier(0)
#define VM(n) { asm volatile("s_waitcnt vmcnt(" #n ")" ::: "memory"); SB(); }
#define LG0BAR() { asm volatile("s_waitcnt lgkmcnt(0)" ::: "memory"); SB(); \
                   __builtin_amdgcn_s_barrier(); SB(); }
#define BARA() { asm volatile("s_waitcnt lgkmcnt(0)" ::: "memory"); SB(); \
                 __builtin_amdgcn_s_barrier(); SB(); }

__global__ __launch_bounds__(512) void local2d_q_kernel(
    const short* __restrict__ xc,
    const float* __restrict__ w,
    short* __restrict__ co)
{
    __shared__ __align__(1024) short Sl[WOFF + COUT * FPAD];  // 160,768 B

    const int hb = blockIdx.x;                  // 256 = i(32) * jt(8)
    const int lb = (hb & 7) * 32 + (hb >> 3);   // XCD-chunked, bijective
    const int i  = lb >> 3;
    const int jt = lb & 7;
    const int j0 = jt * 4;
    const int tid = threadIdx.x;

    const int wave = tid >> 6;
    const int lane = tid & 63;
    const int nt   = wave & 3;
    const int mh   = wave >> 2;
    const int l15  = lane & 15;
    const int lg   = lane >> 4;
    const int lg8  = lg * 8;

    short* WL = Sl + WOFF;

    int rowbyte[5];
#pragma unroll
    for (int mt = 0; mt < 5; ++mt) {
        const int bk = mh * 80 + mt * 16 + l15;
        rowbyte[mt] = (bk * 64 + lg * 16) ^ (((bk >> 1) & 3) << 4);
    }

    float4 wv0[9], wv1[9], wv2[9];
    const f32x4 z4 = {0.f, 0.f, 0.f, 0.f};
    f32x4 acc0, acc1, acc2, acc3, acc4;

#define WISSUE(dst, pp) {                                                  \
        const float* wp = w + (size_t)((i * 32) + j0 + (pp)) * (COUT * FDIM); \
        _Pragma("unroll")                                                  \
        for (int q = 0; q < 9; ++q) {                                      \
            const int g  = tid + q * 512;                                  \
            const int o2 = g / 72;                                         \
            const int f4 = (g - o2 * 72) * 4;                              \
            dst[q] = *reinterpret_cast<const float4*>(wp + o2 * FDIM + f4);\
        } SB(); }

#define SCATTER(src) {                                                     \
        _Pragma("unroll")                                                  \
        for (int q = 0; q < 9; ++q) {                                      \
            const int g  = tid + q * 512;                                  \
            const int o2 = g / 72;                                         \
            const int f4 = (g - o2 * 72) * 4;                              \
            const float vv[4] = {src[q].x, src[q].y, src[q].z, src[q].w};  \
            short* wrow = WL + o2 * FPAD;                                  \
            _Pragma("unroll")                                              \
            for (int e = 0; e < 4; ++e) {                                  \
                const int f = f4 + e; const int c = f / 9;                 \
                const int cell = f - c * 9;                                \
                wrow[cell * 32 + c] = (short)f2bf(vv[e]); } } SB(); }

#define RISSUE(s) {                                                        \
        if (tid < 480) {                                                   \
            _Pragma("unroll")                                              \
            for (int r = 0; r < 4; ++r) {                                  \
                const int u  = tid + r * 480;                              \
                const int pl = u / 640;                                    \
                const int cu = u - pl * 640;                               \
                const short* src = xc + (size_t)((i + pl) * HP + (j0 + 4 + (s))) * PLANE + cu * 8; \
                gl_lds16(src, Sl + (size_t)((s) * SLOT_SH) + (size_t)u * 8); \
            } } SB(); }

#define COMPUTE(p) {                                                       \
        acc0 = z4; acc1 = z4; acc2 = z4; acc3 = z4; acc4 = z4;             \
        const short* bp = WL + (nt * 16 + l15) * FPAD + lg8;               \
        __builtin_amdgcn_s_setprio(1);                                     \
        _Pragma("unroll")                                                  \
        for (int kc = 0; kc < 9; ++kc) {                                   \
            const int kh   = kc / 3;                                       \
            const int kw   = kc - kh * 3;                                  \
            const int slot = ((p) + kw) & 3;                               \
            const char* ab = (const char*)Sl + slot * (SLOT_SH * 2) + kh * (PLANE * 2); \
            const bf16x8 b  = *reinterpret_cast<const bf16x8*>(bp + kc * 32); \
            const bf16x8 a0 = *reinterpret_cast<const bf16x8*>(ab + rowbyte[0]); \
            const bf16x8 a1 = *reinterpret_cast<const bf16x8*>(ab + rowbyte[1]); \
            const bf16x8 a2 = *reinterpret_cast<const bf16x8*>(ab + rowbyte[2]); \
            const bf16x8 a3 = *reinterpret_cast<const bf16x8*>(ab + rowbyte[3]); \
            const bf16x8 a4 = *reinterpret_cast<const bf16x8*>(ab + rowbyte[4]); \
            acc0 = __builtin_amdgcn_mfma_f32_16x16x32_bf16(a0, b, acc0, 0, 0, 0); \
            acc1 = __builtin_amdgcn_mfma_f32_16x16x32_bf16(a1, b, acc1, 0, 0, 0); \
            acc2 = __builtin_amdgcn_mfma_f32_16x16x32_bf16(a2, b, acc2, 0, 0, 0); \
            acc3 = __builtin_amdgcn_mfma_f32_16x16x32_bf16(a3, b, acc3, 0, 0, 0); \
            acc4 = __builtin_amdgcn_mfma_f32_16x16x32_bf16(a4, b, acc4, 0, 0, 0); \
        }                                                                  \
        __builtin_amdgcn_s_setprio(0); }

#define STORE(p) {                                                         \
        const int pix = i * 32 + j0 + (p);                                 \
        const int o3  = nt * 16 + l15;                                     \
        const size_t cb = ((size_t)pix * COUT + o3) * NBK + mh * 80 + lg * 4; \
        { s16x4 s_; s_.x = (short)f2bf(acc0[0]); s_.y = (short)f2bf(acc0[1]); \
          s_.z = (short)f2bf(acc0[2]); s_.w = (short)f2bf(acc0[3]);        \
          *reinterpret_cast<s16x4*>(co + cb + 0) = s_; }                   \
        { s16x4 s_; s_.x = (short)f2bf(acc1[0]); s_.y = (short)f2bf(acc1[1]); \
          s_.z = (short)f2bf(acc1[2]); s_.w = (short)f2bf(acc1[3]);        \
          *reinterpret_cast<s16x4*>(co + cb + 16) = s_; }                  \
        { s16x4 s_; s_.x = (short)f2bf(acc2[0]); s_.y = (short)f2bf(acc2[1]); \
          s_.z = (short)f2bf(acc2[2]); s_.w = (short)f2bf(acc2[3]);        \
          *reinterpret_cast<s16x4*>(co + cb + 32) = s_; }                  \
        { s16x4 s_; s_.x = (short)f2bf(acc3[0]); s_.y = (short)f2bf(acc3[1]); \
          s_.z = (short)f2bf(acc3[2]); s_.w = (short)f2bf(acc3[3]);        \
          *reinterpret_cast<s16x4*>(co + cb + 48) = s_; }                  \
        { s16x4 s_; s_.x = (short)f2bf(acc4[0]); s_.y = (short)f2bf(acc4[1]); \
          s_.z = (short)f2bf(acc4[2]); s_.w = (short)f2bf(acc4[3]);        \
          *reinterpret_cast<s16x4*>(co + cb + 64) = s_; } }

    // ================= prologue =================
    WISSUE(wv0, 0)                           // [W0:9]
    WISSUE(wv1, 1)                           // [W0:9 W1:9]
    {
#pragma unroll
        for (int r = 0; r < 15; ++r) {       // SLOTS
            const int u   = tid + r * 512;
            const int s   = u / 1920;
            const int rem = u - s * 1920;
            const int pl  = rem / 640;
            const int cu  = rem - pl * 640;
            const short* src = xc + (size_t)((i + pl) * HP + (j0 + s)) * PLANE + cu * 8;
            gl_lds16(src, Sl + (size_t)u * 8);
        }
        SB();
    }                                        // [W0:9 W1:9 S:15] = 33
    VM(24)                                   // W0 done
    SCATTER(wv0)
    VM(9)                                    // S done (W1 remains)
    LG0BAR()                                 // WL=w(0), slots 0-3 ready

    // ================= phase 0 =================
    WISSUE(wv2, 2)                           // [W1:9 W2:9]
    COMPUTE(0) STORE(0)                      // [W1:9 W2:9 st0:5]
    BARA()
    VM(14)                                   // W1 done (W2+st0=14)
    SCATTER(wv1)
    LG0BAR()                                 // WL=w(1)

    // ================= phase 1 =================
    RISSUE(0)                                // [W2:9 st0:5 R0:4]
    WISSUE(wv0, 3)                           // [... W3:9] = 27
    COMPUTE(1) STORE(1)                      // [... st1:5] = 32
    BARA()
    VM(23)                                   // W2 done
    SCATTER(wv2)
    VM(14)                                   // R0 done (W3:9+st1:5)
    LG0BAR()                                 // WL=w(2), slot0 ready

    // ================= phase 2 =================
    RISSUE(1)                                // [W3:9 st1:5 R1:4]
    COMPUTE(2) STORE(2)                      // [... st2:5] = 23
    BARA()
    VM(14)                                   // W3 done (st1+R1+st2=14)
    SCATTER(wv0)
    VM(5)                                    // R1 done (st2 remains)
    LG0BAR()                                 // WL=w(3), slot1 ready

    // ================= phase 3 =================
    COMPUTE(3) STORE(3)

#undef WISSUE
#undef SCATTER
#undef RISSUE
#undef COMPUTE
#undef STORE
}

// ---- t2 ----
__global__ __launch_bounds__(256) void t2_kernel(
    const short* __restrict__ co,
    const float* __restrict__ bias,
    float* __restrict__ out)
{
    __shared__ short tl[32][36];
    const int b    = blockIdx.x;          // 10240 = o(64) * bkT(5) * pixT(32)
    const int o    = b & 63;
    const int rest = b >> 6;
    const int bkT  = rest % 5;
    const int pixT = rest / 5;
    const int tid  = threadIdx.x;
    {
        const int p  = tid >> 3;
        const int bq = tid & 7;
        const int pix = pixT * 32 + p;
        const s16x4 v = *reinterpret_cast<const s16x4*>(
            co + ((size_t)pix * COUT + o) * NBK + bkT * 32 + bq * 4);
        *reinterpret_cast<s16x4*>(&tl[p][bq * 4]) = v;
    }
    __syncthreads();
    {
        const int bb = tid >> 3;
        const int pq = tid & 7;
        const int bk = bkT * 32 + bb;
        const int k  = bk % 10;
        const size_t pbase = (size_t)pixT * 32 + pq * 4;
        const float4 bv = *reinterpret_cast<const float4*>(
            bias + ((size_t)(k * COUT + o) << 10) + pbase);
        float4 r;
        r.x = __uint_as_float(((unsigned)(unsigned short)tl[pq * 4 + 0][bb]) << 16) + bv.x;
        r.y = __uint_as_float(((unsigned)(unsigned short)tl[pq * 4 + 1][bb]) << 16) + bv.y;
        r.z = __uint_as_float(((unsigned)(unsigned short)tl[pq * 4 + 2][bb]) << 16) + bv.z;
        r.w = __uint_as_float(((unsigned)(unsigned short)tl[pq * 4 + 3][bb]) << 16) + bv.w;
        *reinterpret_cast<float4*>(out + ((size_t)(bk * COUT + o) << 10) + pbase) = r;
    }
}

// ================= R3 fallback (proven; needs 10 MB ws) =================
__global__ __launch_bounds__(256) void xpose_kernel(
    const float* __restrict__ x, short* __restrict__ xc)
{
    __shared__ short tile[HW][36];
    const int bid = blockIdx.x;
    const int bk  = bid >> 5;
    const int h   = bid & 31;
    const int tid = threadIdx.x;
    {
        const int c  = tid >> 3;
        const int w4 = (tid & 7) * 4;
        const float4 v = *reinterpret_cast<const float4*>(
            x + (size_t)(bk * 32 + c) * 1024 + h * 32 + w4);
        tile[w4 + 0][c] = (short)f2bf(v.x);
        tile[w4 + 1][c] = (short)f2bf(v.y);
        tile[w4 + 2][c] = (short)f2bf(v.z);
        tile[w4 + 3][c] = (short)f2bf(v.w);
    }
    __syncthreads();
    {
        const int w  = tid >> 3;
        const int cq = tid & 7;
        const uint2 pk = *reinterpret_cast<const uint2*>(&tile[w][cq * 4]);
        *reinterpret_cast<uint2*>(
            xc + ((size_t)(bk * 1024 + h * 32 + w) * 32 + cq * 4)) = pk;
    }
}

__global__ __launch_bounds__(512, 4) void local2d_mfma2_kernel(
    const short* __restrict__ xc,
    const float* __restrict__ w,
    const float* __restrict__ bias,
    float* __restrict__ out)
{
    __shared__ short Wl[COUT * FPAD];
    const int hb  = blockIdx.x;
    const int lb  = (hb & 7) * 128 + (hb >> 3);
    const int i   = lb >> 5;
    const int j   = lb & 31;
    const int pix = i * HW + j;
    const int tid = threadIdx.x;
    {
        const float* wp = w + (size_t)pix * (COUT * FDIM);
#pragma unroll
        for (int p = 0; p < 9; ++p) {
            const int g  = tid + p * 512;
            const int o  = g / 72;
            const int f4 = (g - o * 72) * 4;
            const float4 v = *reinterpret_cast<const float4*>(wp + o * FDIM + f4);
            const float vv[4] = {v.x, v.y, v.z, v.w};
            short* wrow = &Wl[o * FPAD];
#pragma unroll
            for (int e = 0; e < 4; ++e) {
                const int f    = f4 + e;
                const int c    = f / 9;
                const int cell = f - c * 9;
                wrow[cell * 32 + c] = (short)f2bf(vv[e]);
            }
        }
    }
    __syncthreads();
    const int wave = tid >> 6;
    const int lane = tid & 63;
    const int nt   = wave & 3;
    const int mh   = wave >> 2;
    const int l15  = lane & 15;
    const int lg8  = (lane >> 4) * 8;
    f32x4 acc[5];
#pragma unroll
    for (int mt = 0; mt < 5; ++mt)
#pragma unroll
        for (int r = 0; r < 4; ++r) acc[mt][r] = 0.f;
    const short* xb[5];
#pragma unroll
    for (int mt = 0; mt < 5; ++mt) {
        const int bk = mh * 80 + mt * 16 + l15;
        xb[mt] = xc + (size_t)bk * (HW * HW * CIN) + lg8;
    }
    const short* bp = &Wl[(nt * 16 + l15) * FPAD + lg8];
#pragma unroll
    for (int kc = 0; kc < 9; ++kc) {
        const int kh = kc / 3;
        const int kw = kc - kh * 3;
        const int ih = i - 1 + kh;
        const int jw = j - 1 + kw;
        if ((unsigned)ih >= (unsigned)HW || (unsigned)jw >= (unsigned)HW)
            continue;
        const bf16x8 b = *reinterpret_cast<const bf16x8*>(bp + kc * 32);
        const int xoff = (ih * HW + jw) * CIN;
#pragma unroll
        for (int mt = 0; mt < 5; ++mt) {
            const bf16x8 a = *reinterpret_cast<const bf16x8*>(xb[mt] + xoff);
            acc[mt] = __builtin_amdgcn_mfma_f32_16x16x32_bf16(a, b, acc[mt], 0, 0, 0);
        }
    }
    const int o  = nt * 16 + l15;
    const int r0 = (lane >> 4) * 4;
#pragma unroll
    for (int mt = 0; mt < 5; ++mt) {
        const int bk0 = mh * 80 + mt * 16 + r0;
#pragma unroll
        for (int r = 0; r < 4; ++r) {
            const int bk = bk0 + r;
            const int k  = bk % 10;
            out[((size_t)(bk * COUT + o) << 10) + pix] =
                acc[mt][r] + bias[((size_t)(k * COUT + o) << 10) + pix];
        }
    }
}

extern "C" void kernel_launch(void* const* d_in, const int* in_sizes, int n_in,
                              void* d_out, int out_size, void* d_ws, size_t ws_size,
                              hipStream_t stream) {
    const float* x    = (const float*)d_in[0];
    const float* w    = (const float*)d_in[1];
    const float* bias = (const float*)d_in[2];
    float* out        = (float*)d_out;

    if (ws_size >= XC_BYTES + CO_BYTES) {
        short* xc = (short*)d_ws;
        short* co = (short*)((char*)d_ws + XC_BYTES);
        hipLaunchKernelGGL(hz_kernel, dim3(132), dim3(256), 0, stream, xc);
        hipLaunchKernelGGL(t1_kernel, dim3(5120), dim3(256), 0, stream, x, xc);
        hipLaunchKernelGGL(local2d_q_kernel, dim3(256), dim3(512), 0, stream,
                           xc, w, co);
        hipLaunchKernelGGL(t2_kernel, dim3(10240), dim3(256), 0, stream,
                           co, bias, out);
    } else {
        short* xc = (short*)d_ws;
        hipLaunchKernelGGL(xpose_kernel, dim3(5120), dim3(256), 0, stream, x, xc);
        hipLaunchKernelGGL(local2d_mfma2_kernel, dim3(1024), dim3(512), 0, stream,
                           xc, w, bias, out);
    }
}

// Round 12
// 52.072 us; speedup vs baseline: 4.2681x; 1.0180x over previous
//
#include <hip/hip_runtime.h>

// VecLocal2d R12 = R11 with ALL hot-path LDS ops as inline asm (opaque to
// compiler). Theory: compiler-inserted conservative waitcnt before its
// tracked LDS reads (which alias global_load_lds dest) drained the whole
// VMEM queue every phase, making W fetch serial regardless of my counted
// ledger (explains R4-R11 all ~40us, depth-insensitive). Now:
//   - COMPUTE: asm ds_read_b128, 2-bank ping-pong, counted lgkmcnt(6),
//     sched_barrier(0) after each wait (rule #18).
//   - SCATTER: asm ds_write_b16.
//   - Compiler sees NO LDS deps -> cannot insert drains; my R11 vmcnt
//     ledger (unchanged) is the only sync.
// hz/t1(pre-swizzled)/t2/fallback + schedule/ledger verbatim from R11.

#define HW    32
#define CIN   32
#define COUT  64
#define FDIM  288
#define FPAD  296
#define NBK   160
#define HP    34
#define PLANE (NBK * CIN)      // 5120 shorts per (ih,jw) plane
#define SLOT_SH (3 * PLANE)    // 15360 shorts per jw-slot
#define WOFF  (4 * SLOT_SH)    // 61440 shorts: W region start

using f32x4  = __attribute__((ext_vector_type(4))) float;
using bf16x8 = __attribute__((ext_vector_type(8))) short;
using s16x4  = __attribute__((ext_vector_type(4))) short;

static __device__ inline unsigned short f2bf(float f) {
    unsigned u = __float_as_uint(f);
    u += 0x7FFFu + ((u >> 16) & 1u);   // round-to-nearest-even
    return (unsigned short)(u >> 16);
}
static __device__ inline void gl_lds16(const short* src, short* dst) {
    __builtin_amdgcn_global_load_lds(
        (const __attribute__((address_space(1))) unsigned int*)src,
        (__attribute__((address_space(3))) unsigned int*)dst, 16, 0, 0);
}
static constexpr size_t XC_BYTES = (size_t)HP * HP * PLANE * 2;       // 11,837,440
static constexpr size_t CO_BYTES = (size_t)1024 * COUT * NBK * 2;     // 20,971,520

// ---- hz ----
__global__ __launch_bounds__(256) void hz_kernel(short* __restrict__ xc)
{
    const int id = blockIdx.x;
    int h, w;
    if (id < 34)      { h = 0;  w = id; }
    else if (id < 68) { h = 33; w = id - 34; }
    else { const int e = id - 68; h = 1 + (e >> 1); w = (e & 1) * 33; }
    uint2* p = reinterpret_cast<uint2*>(xc + (size_t)(h * HP + w) * PLANE);
    const uint2 z = {0u, 0u};
#pragma unroll
    for (int r = 0; r < 5; ++r)
        p[threadIdx.x + r * 256] = z;
}

// ---- t1 (pre-swizzled planes) ----
__global__ __launch_bounds__(256) void t1_kernel(
    const float* __restrict__ x, short* __restrict__ xc)
{
    __shared__ short tile[HW][36];
    const int bid = blockIdx.x;
    const int bk  = bid >> 5;
    const int h   = bid & 31;
    const int tid = threadIdx.x;
    {
        const int c  = tid >> 3;
        const int w4 = (tid & 7) * 4;
        const float4 v = *reinterpret_cast<const float4*>(
            x + (size_t)(bk * 32 + c) * 1024 + h * 32 + w4);
        tile[w4 + 0][c] = (short)f2bf(v.x);
        tile[w4 + 1][c] = (short)f2bf(v.y);
        tile[w4 + 2][c] = (short)f2bf(v.z);
        tile[w4 + 3][c] = (short)f2bf(v.w);
    }
    __syncthreads();
    {
        const int w  = tid >> 3;
        const int cq = tid & 7;
        const uint2 pk = *reinterpret_cast<const uint2*>(&tile[w][cq * 4]);
        const int sidx = bk * 32 + ((cq * 4) ^ (((bk >> 1) & 3) << 3));
        *reinterpret_cast<uint2*>(
            xc + (size_t)((h + 1) * HP + (w + 1)) * PLANE + sidx) = pk;
    }
}

// ---- main ----
#define SB()  __builtin_amdgcn_sched_barrier(0)
#define VM(n) { asm volatile("s_waitcnt vmcnt(" #n ")" ::: "memory"); SB(); }
#define LGK(n) { asm volatile("s_waitcnt lgkmcnt(" #n ")"); SB(); }
#define LG0BAR() { asm volatile("s_waitcnt lgkmcnt(0)" ::: "memory"); SB(); \
                   __builtin_amdgcn_s_barrier(); SB(); }
#define BARA() { asm volatile("s_waitcnt lgkmcnt(0)" ::: "memory"); SB(); \
                 __builtin_amdgcn_s_barrier(); SB(); }

__global__ __launch_bounds__(512) void local2d_r_kernel(
    const short* __restrict__ xc,
    const float* __restrict__ w,
    short* __restrict__ co)
{
    __shared__ __align__(1024) short Sl[WOFF + COUT * FPAD];  // 160,768 B

    const int hb = blockIdx.x;                  // 256 = i(32) * jt(8)
    const int lb = (hb & 7) * 32 + (hb >> 3);   // XCD-chunked, bijective
    const int i  = lb >> 3;
    const int jt = lb & 7;
    const int j0 = jt * 4;
    const int tid = threadIdx.x;

    const int wave = tid >> 6;
    const int lane = tid & 63;
    const int nt   = wave & 3;
    const int mh   = wave >> 2;
    const int l15  = lane & 15;
    const int lg   = lane >> 4;
    const int lg8  = lg * 8;

    // LDS byte-base (AS3 offset; same cast pattern as gl_lds16, proven)
    const unsigned sbase =
        (unsigned)(size_t)(__attribute__((address_space(3))) short*)Sl;
    const unsigned wbase = sbase + (unsigned)(WOFF * 2)
                         + (unsigned)(((nt * 16 + l15) * FPAD + lg8) * 2);

    unsigned rbv[5];
#pragma unroll
    for (int mt = 0; mt < 5; ++mt) {
        const int bk = mh * 80 + mt * 16 + l15;
        rbv[mt] = (unsigned)((bk * 64 + lg * 16) ^ (((bk >> 1) & 3) << 4));
    }
    const unsigned rb0 = rbv[0], rb1 = rbv[1], rb2 = rbv[2],
                   rb3 = rbv[3], rb4 = rbv[4];

    float4 wv0[9], wv1[9], wv2[9];
    const f32x4 z4 = {0.f, 0.f, 0.f, 0.f};
    f32x4 acc0, acc1, acc2, acc3, acc4;

#define WISSUE(dst, pp) {                                                  \
        const float* wp = w + (size_t)((i * 32) + j0 + (pp)) * (COUT * FDIM); \
        _Pragma("unroll")                                                  \
        for (int q = 0; q < 9; ++q) {                                      \
            const int g  = tid + q * 512;                                  \
            const int o2 = g / 72;                                         \
            const int f4 = (g - o2 * 72) * 4;                              \
            dst[q] = *reinterpret_cast<const float4*>(wp + o2 * FDIM + f4);\
        } SB(); }

#define SCATTER(src) {                                                     \
        _Pragma("unroll")                                                  \
        for (int q = 0; q < 9; ++q) {                                      \
            const int g  = tid + q * 512;                                  \
            const int o2 = g / 72;                                         \
            const int f4 = (g - o2 * 72) * 4;                              \
            const float vv[4] = {src[q].x, src[q].y, src[q].z, src[q].w};  \
            const unsigned wrow = sbase + (unsigned)(WOFF * 2)             \
                                + (unsigned)(o2 * (FPAD * 2));             \
            _Pragma("unroll")                                              \
            for (int e = 0; e < 4; ++e) {                                  \
                const int f = f4 + e; const int c = f / 9;                 \
                const int cell = f - c * 9;                                \
                const unsigned a_ = wrow + (unsigned)((cell * 32 + c) * 2);\
                const unsigned v_ = (unsigned)f2bf(vv[e]);                 \
                asm volatile("ds_write_b16 %0, %1" :: "v"(a_), "v"(v_));   \
            } } SB(); }

#define RISSUE(s) {                                                        \
        if (tid < 480) {                                                   \
            _Pragma("unroll")                                              \
            for (int r = 0; r < 4; ++r) {                                  \
                const int u  = tid + r * 480;                              \
                const int pl = u / 640;                                    \
                const int cu = u - pl * 640;                               \
                const short* src = xc + (size_t)((i + pl) * HP + (j0 + 4 + (s))) * PLANE + cu * 8; \
                gl_lds16(src, Sl + (size_t)((s) * SLOT_SH) + (size_t)u * 8); \
            } } SB(); }

#define RD6(A0, A1, A2, A3, A4, BB, p, kc) {                               \
        constexpr int kh_ = (kc) / 3, kw_ = (kc) - ((kc) / 3) * 3;         \
        const int slot_ = ((p) + kw_) & 3;                                 \
        const unsigned ab_ = sbase                                         \
            + (unsigned)(slot_ * (SLOT_SH * 2)) + (unsigned)(kh_ * (PLANE * 2)); \
        asm volatile("ds_read_b128 %0, %1" : "=v"(BB) : "v"(wbase + (kc) * 64)); \
        asm volatile("ds_read_b128 %0, %1" : "=v"(A0) : "v"(ab_ + rb0));   \
        asm volatile("ds_read_b128 %0, %1" : "=v"(A1) : "v"(ab_ + rb1));   \
        asm volatile("ds_read_b128 %0, %1" : "=v"(A2) : "v"(ab_ + rb2));   \
        asm volatile("ds_read_b128 %0, %1" : "=v"(A3) : "v"(ab_ + rb3));   \
        asm volatile("ds_read_b128 %0, %1" : "=v"(A4) : "v"(ab_ + rb4)); }

#define MM5(A0, A1, A2, A3, A4, BB) {                                      \
        acc0 = __builtin_amdgcn_mfma_f32_16x16x32_bf16(A0, BB, acc0, 0, 0, 0); \
        acc1 = __builtin_amdgcn_mfma_f32_16x16x32_bf16(A1, BB, acc1, 0, 0, 0); \
        acc2 = __builtin_amdgcn_mfma_f32_16x16x32_bf16(A2, BB, acc2, 0, 0, 0); \
        acc3 = __builtin_amdgcn_mfma_f32_16x16x32_bf16(A3, BB, acc3, 0, 0, 0); \
        acc4 = __builtin_amdgcn_mfma_f32_16x16x32_bf16(A4, BB, acc4, 0, 0, 0); }

#define COMPUTE(p) {                                                       \
        acc0 = z4; acc1 = z4; acc2 = z4; acc3 = z4; acc4 = z4;             \
        bf16x8 fA0, fA1, fA2, fA3, fA4, fB, gA0, gA1, gA2, gA3, gA4, gB;   \
        __builtin_amdgcn_s_setprio(1);                                     \
        RD6(fA0, fA1, fA2, fA3, fA4, fB, p, 0)                             \
        RD6(gA0, gA1, gA2, gA3, gA4, gB, p, 1)                             \
        LGK(6) MM5(fA0, fA1, fA2, fA3, fA4, fB)                            \
        RD6(fA0, fA1, fA2, fA3, fA4, fB, p, 2)                             \
        LGK(6) MM5(gA0, gA1, gA2, gA3, gA4, gB)                            \
        RD6(gA0, gA1, gA2, gA3, gA4, gB, p, 3)                             \
        LGK(6) MM5(fA0, fA1, fA2, fA3, fA4, fB)                            \
        RD6(fA0, fA1, fA2, fA3, fA4, fB, p, 4)                             \
        LGK(6) MM5(gA0, gA1, gA2, gA3, gA4, gB)                            \
        RD6(gA0, gA1, gA2, gA3, gA4, gB, p, 5)                             \
        LGK(6) MM5(fA0, fA1, fA2, fA3, fA4, fB)                            \
        RD6(fA0, fA1, fA2, fA3, fA4, fB, p, 6)                             \
        LGK(6) MM5(gA0, gA1, gA2, gA3, gA4, gB)                            \
        RD6(gA0, gA1, gA2, gA3, gA4, gB, p, 7)                             \
        LGK(6) MM5(fA0, fA1, fA2, fA3, fA4, fB)                            \
        RD6(fA0, fA1, fA2, fA3, fA4, fB, p, 8)                             \
        LGK(6) MM5(gA0, gA1, gA2, gA3, gA4, gB)                            \
        LGK(0) MM5(fA0, fA1, fA2, fA3, fA4, fB)                            \
        __builtin_amdgcn_s_setprio(0); }

#define STORE(p) {                                                         \
        const int pix = i * 32 + j0 + (p);                                 \
        const int o3  = nt * 16 + l15;                                     \
        const size_t cb = ((size_t)pix * COUT + o3) * NBK + mh * 80 + lg * 4; \
        { s16x4 s_; s_.x = (short)f2bf(acc0[0]); s_.y = (short)f2bf(acc0[1]); \
          s_.z = (short)f2bf(acc0[2]); s_.w = (short)f2bf(acc0[3]);        \
          *reinterpret_cast<s16x4*>(co + cb + 0) = s_; }                   \
        { s16x4 s_; s_.x = (short)f2bf(acc1[0]); s_.y = (short)f2bf(acc1[1]); \
          s_.z = (short)f2bf(acc1[2]); s_.w = (short)f2bf(acc1[3]);        \
          *reinterpret_cast<s16x4*>(co + cb + 16) = s_; }                  \
        { s16x4 s_; s_.x = (short)f2bf(acc2[0]); s_.y = (short)f2bf(acc2[1]); \
          s_.z = (short)f2bf(acc2[2]); s_.w = (short)f2bf(acc2[3]);        \
          *reinterpret_cast<s16x4*>(co + cb + 32) = s_; }                  \
        { s16x4 s_; s_.x = (short)f2bf(acc3[0]); s_.y = (short)f2bf(acc3[1]); \
          s_.z = (short)f2bf(acc3[2]); s_.w = (short)f2bf(acc3[3]);        \
          *reinterpret_cast<s16x4*>(co + cb + 48) = s_; }                  \
        { s16x4 s_; s_.x = (short)f2bf(acc4[0]); s_.y = (short)f2bf(acc4[1]); \
          s_.z = (short)f2bf(acc4[2]); s_.w = (short)f2bf(acc4[3]);        \
          *reinterpret_cast<s16x4*>(co + cb + 64) = s_; } }

    // ================= prologue =================
    WISSUE(wv0, 0)                           // [W0:9]
    WISSUE(wv1, 1)                           // [W0:9 W1:9]
    {
#pragma unroll
        for (int r = 0; r < 15; ++r) {       // SLOTS
            const int u   = tid + r * 512;
            const int s   = u / 1920;
            const int rem = u - s * 1920;
            const int pl  = rem / 640;
            const int cu  = rem - pl * 640;
            const short* src = xc + (size_t)((i + pl) * HP + (j0 + s)) * PLANE + cu * 8;
            gl_lds16(src, Sl + (size_t)u * 8);
        }
        SB();
    }                                        // [W0:9 W1:9 S:15] = 33
    VM(24)                                   // W0 done
    SCATTER(wv0)
    VM(9)                                    // S done (W1 remains)
    LG0BAR()                                 // WL=w(0), slots 0-3 ready

    // ================= phase 0 =================
    WISSUE(wv2, 2)                           // [W1:9 W2:9]
    COMPUTE(0) STORE(0)                      // [W1:9 W2:9 st0:5]
    BARA()
    VM(14)                                   // W1 done (W2+st0=14)
    SCATTER(wv1)
    LG0BAR()                                 // WL=w(1)

    // ================= phase 1 =================
    RISSUE(0)                                // [W2:9 st0:5 R0:4]
    WISSUE(wv0, 3)                           // [... W3:9] = 27
    COMPUTE(1) STORE(1)                      // [... st1:5] = 32
    BARA()
    VM(23)                                   // W2 done
    SCATTER(wv2)
    VM(14)                                   // R0 done (W3:9+st1:5)
    LG0BAR()                                 // WL=w(2), slot0 ready

    // ================= phase 2 =================
    RISSUE(1)                                // [W3:9 st1:5 R1:4]
    COMPUTE(2) STORE(2)                      // [... st2:5] = 23
    BARA()
    VM(14)                                   // W3 done (st1+R1+st2=14)
    SCATTER(wv0)
    VM(5)                                    // R1 done (st2 remains)
    LG0BAR()                                 // WL=w(3), slot1 ready

    // ================= phase 3 =================
    COMPUTE(3) STORE(3)

#undef WISSUE
#undef SCATTER
#undef RISSUE
#undef RD6
#undef MM5
#undef COMPUTE
#undef STORE
}

// ---- t2 ----
__global__ __launch_bounds__(256) void t2_kernel(
    const short* __restrict__ co,
    const float* __restrict__ bias,
    float* __restrict__ out)
{
    __shared__ short tl[32][36];
    const int b    = blockIdx.x;          // 10240 = o(64) * bkT(5) * pixT(32)
    const int o    = b & 63;
    const int rest = b >> 6;
    const int bkT  = rest % 5;
    const int pixT = rest / 5;
    const int tid  = threadIdx.x;
    {
        const int p  = tid >> 3;
        const int bq = tid & 7;
        const int pix = pixT * 32 + p;
        const s16x4 v = *reinterpret_cast<const s16x4*>(
            co + ((size_t)pix * COUT + o) * NBK + bkT * 32 + bq * 4);
        *reinterpret_cast<s16x4*>(&tl[p][bq * 4]) = v;
    }
    __syncthreads();
    {
        const int bb = tid >> 3;
        const int pq = tid & 7;
        const int bk = bkT * 32 + bb;
        const int k  = bk % 10;
        const size_t pbase = (size_t)pixT * 32 + pq * 4;
        const float4 bv = *reinterpret_cast<const float4*>(
            bias + ((size_t)(k * COUT + o) << 10) + pbase);
        float4 r;
        r.x = __uint_as_float(((unsigned)(unsigned short)tl[pq * 4 + 0][bb]) << 16) + bv.x;
        r.y = __uint_as_float(((unsigned)(unsigned short)tl[pq * 4 + 1][bb]) << 16) + bv.y;
        r.z = __uint_as_float(((unsigned)(unsigned short)tl[pq * 4 + 2][bb]) << 16) + bv.z;
        r.w = __uint_as_float(((unsigned)(unsigned short)tl[pq * 4 + 3][bb]) << 16) + bv.w;
        *reinterpret_cast<float4*>(out + ((size_t)(bk * COUT + o) << 10) + pbase) = r;
    }
}

// ================= R3 fallback (proven; needs 10 MB ws) =================
__global__ __launch_bounds__(256) void xpose_kernel(
    const float* __restrict__ x, short* __restrict__ xc)
{
    __shared__ short tile[HW][36];
    const int bid = blockIdx.x;
    const int bk  = bid >> 5;
    const int h   = bid & 31;
    const int tid = threadIdx.x;
    {
        const int c  = tid >> 3;
        const int w4 = (tid & 7) * 4;
        const float4 v = *reinterpret_cast<const float4*>(
            x + (size_t)(bk * 32 + c) * 1024 + h * 32 + w4);
        tile[w4 + 0][c] = (short)f2bf(v.x);
        tile[w4 + 1][c] = (short)f2bf(v.y);
        tile[w4 + 2][c] = (short)f2bf(v.z);
        tile[w4 + 3][c] = (short)f2bf(v.w);
    }
    __syncthreads();
    {
        const int w  = tid >> 3;
        const int cq = tid & 7;
        const uint2 pk = *reinterpret_cast<const uint2*>(&tile[w][cq * 4]);
        *reinterpret_cast<uint2*>(
            xc + ((size_t)(bk * 1024 + h * 32 + w) * 32 + cq * 4)) = pk;
    }
}

__global__ __launch_bounds__(512, 4) void local2d_mfma2_kernel(
    const short* __restrict__ xc,
    const float* __restrict__ w,
    const float* __restrict__ bias,
    float* __restrict__ out)
{
    __shared__ short Wl[COUT * FPAD];
    const int hb  = blockIdx.x;
    const int lb  = (hb & 7) * 128 + (hb >> 3);
    const int i   = lb >> 5;
    const int j   = lb & 31;
    const int pix = i * HW + j;
    const int tid = threadIdx.x;
    {
        const float* wp = w + (size_t)pix * (COUT * FDIM);
#pragma unroll
        for (int p = 0; p < 9; ++p) {
            const int g  = tid + p * 512;
            const int o  = g / 72;
            const int f4 = (g - o * 72) * 4;
            const float4 v = *reinterpret_cast<const float4*>(wp + o * FDIM + f4);
            const float vv[4] = {v.x, v.y, v.z, v.w};
            short* wrow = &Wl[o * FPAD];
#pragma unroll
            for (int e = 0; e < 4; ++e) {
                const int f    = f4 + e;
                const int c    = f / 9;
                const int cell = f - c * 9;
                wrow[cell * 32 + c] = (short)f2bf(vv[e]);
            }
        }
    }
    __syncthreads();
    const int wave = tid >> 6;
    const int lane = tid & 63;
    const int nt   = wave & 3;
    const int mh   = wave >> 2;
    const int l15  = lane & 15;
    const int lg8  = (lane >> 4) * 8;
    f32x4 acc[5];
#pragma unroll
    for (int mt = 0; mt < 5; ++mt)
#pragma unroll
        for (int r = 0; r < 4; ++r) acc[mt][r] = 0.f;
    const short* xb[5];
#pragma unroll
    for (int mt = 0; mt < 5; ++mt) {
        const int bk = mh * 80 + mt * 16 + l15;
        xb[mt] = xc + (size_t)bk * (HW * HW * CIN) + lg8;
    }
    const short* bp = &Wl[(nt * 16 + l15) * FPAD + lg8];
#pragma unroll
    for (int kc = 0; kc < 9; ++kc) {
        const int kh = kc / 3;
        const int kw = kc - kh * 3;
        const int ih = i - 1 + kh;
        const int jw = j - 1 + kw;
        if ((unsigned)ih >= (unsigned)HW || (unsigned)jw >= (unsigned)HW)
            continue;
        const bf16x8 b = *reinterpret_cast<const bf16x8*>(bp + kc * 32);
        const int xoff = (ih * HW + jw) * CIN;
#pragma unroll
        for (int mt = 0; mt < 5; ++mt) {
            const bf16x8 a = *reinterpret_cast<const bf16x8*>(xb[mt] + xoff);
            acc[mt] = __builtin_amdgcn_mfma_f32_16x16x32_bf16(a, b, acc[mt], 0, 0, 0);
        }
    }
    const int o  = nt * 16 + l15;
    const int r0 = (lane >> 4) * 4;
#pragma unroll
    for (int mt = 0; mt < 5; ++mt) {
        const int bk0 = mh * 80 + mt * 16 + r0;
#pragma unroll
        for (int r = 0; r < 4; ++r) {
            const int bk = bk0 + r;
            const int k  = bk % 10;
            out[((size_t)(bk * COUT + o) << 10) + pix] =
                acc[mt][r] + bias[((size_t)(k * COUT + o) << 10) + pix];
        }
    }
}

extern "C" void kernel_launch(void* const* d_in, const int* in_sizes, int n_in,
                              void* d_out, int out_size, void* d_ws, size_t ws_size,
                              hipStream_t stream) {
    const float* x    = (const float*)d_in[0];
    const float* w    = (const float*)d_in[1];
    const float* bias = (const float*)d_in[2];
    float* out        = (float*)d_out;

    if (ws_size >= XC_BYTES + CO_BYTES) {
        short* xc = (short*)d_ws;
        short* co = (short*)((char*)d_ws + XC_BYTES);
        hipLaunchKernelGGL(hz_kernel, dim3(132), dim3(256), 0, stream, xc);
        hipLaunchKernelGGL(t1_kernel, dim3(5120), dim3(256), 0, stream, x, xc);
        hipLaunchKernelGGL(local2d_r_kernel, dim3(256), dim3(512), 0, stream,
                           xc, w, co);
        hipLaunchKernelGGL(t2_kernel, dim3(10240), dim3(256), 0, stream,
                           co, bias, out);
    } else {
        short* xc = (short*)d_ws;
        hipLaunchKernelGGL(xpose_kernel, dim3(5120), dim3(256), 0, stream, x, xc);
        hipLaunchKernelGGL(local2d_mfma2_kernel, dim3(1024), dim3(512), 0, stream,
                           xc, w, bias, out);
    }
}